// Round 15
// baseline (149.636 us; speedup 1.0000x reference)
//
#include <hip/hip_runtime.h>
#include <stdint.h>

// Inv2d fused pipeline, MI355X gfx950.
// B=16, C=256, H=W=64, K2=9. All inputs fp32; internal GEMMs in bf16 MFMA.
//
// Pipeline: prep -> k1 (GEMM1 + fused BN partial stats) -> bn_final ->
// bn_apply -> k3 v15 (proven round-12 schedule widened to 512 threads /
// BN=512: 8 waves x 64 cols, 2-deep A staging via global_load_lds with
// both-sides swizzle, B global->reg 2-deep, counted per-wave vmcnt,
// swapped-operand epilogue with LDS X tile).
//
// ws layout:
//   Wr (bf16, tiled [b][slab=c/32][p][c%32])      : 33,554,432 B
//   w_reduce bf16 tiled [ks][o][32]               :    131,072 B
//   w_span  bf16 tiled [ks][mt][phys=k2*16+g][32] :  1,179,648 B
//   part [c][512][2] f32 partial sums             :  1,048,576 B
//   coeffs [c][2] f32 (A=gamma*rstd, B=beta-mean*A):      2,048 B

typedef __attribute__((ext_vector_type(4))) float f32x4;
typedef __attribute__((ext_vector_type(8))) short s16x8;
typedef __attribute__((ext_vector_type(8))) __bf16 bf16x8;

#define WAITV(N) asm volatile("s_waitcnt vmcnt(" #N ")" ::: "memory")
#define WAITL0   asm volatile("s_waitcnt lgkmcnt(0)" ::: "memory")
#define PIN()    asm volatile("" ::: "memory")
#define BAR()    do { PIN(); __builtin_amdgcn_s_barrier(); PIN(); } while (0)

__device__ __forceinline__ float bf2f(uint16_t u){
  union { uint32_t i; float f; } v; v.i = ((uint32_t)u) << 16; return v.f;
}
__device__ __forceinline__ uint16_t f2bf(float f){
  __bf16 h = (__bf16)f;                       // compiler RNE cvt (m240)
  return __builtin_bit_cast(uint16_t, h);
}

// SFINAE shim: prefer short8 operands; fall back to __bf16 vec.
template <typename V>
__device__ __forceinline__ auto mfma16x16x32(V a, V b, f32x4 c, int)
    -> decltype(__builtin_amdgcn_mfma_f32_16x16x32_bf16(a, b, c, 0, 0, 0)) {
  return __builtin_amdgcn_mfma_f32_16x16x32_bf16(a, b, c, 0, 0, 0);
}
template <typename V>
__device__ __forceinline__ f32x4 mfma16x16x32(V a, V b, f32x4 c, long) {
  bf16x8 aa = __builtin_bit_cast(bf16x8, a);
  bf16x8 bb = __builtin_bit_cast(bf16x8, b);
  return __builtin_amdgcn_mfma_f32_16x16x32_bf16(aa, bb, c, 0, 0, 0);
}

typedef uint32_t u32_g __attribute__((address_space(1)));
typedef uint32_t u32_l __attribute__((address_space(3)));
__device__ __forceinline__ void glds16(const void* g, void* l){
  __builtin_amdgcn_global_load_lds((const u32_g*)g, (u32_l*)l, 16, 0, 0);
}

// ---------------- kernel 0: weight convert + pre-tile ----------------
__global__ __launch_bounds__(256) void prep_weights(
    const float* __restrict__ wred, const float* __restrict__ wsp,
    uint16_t* __restrict__ wrt, uint16_t* __restrict__ wspt){
  int id = blockIdx.x * 256 + threadIdx.x;   // 16B-chunk id, 320*256 = 81920 total
  union { uint4 v; uint16_t h[8]; } u;
  if (id < 8192){                            // w_reduce: [ks][o][32]
    int ks = id >> 10;
    int o  = (id >> 2) & 255;
    int j0 = (id & 3) * 8;
    const float* s = wred + o * 256 + ks * 32 + j0;
    #pragma unroll
    for (int i = 0; i < 8; i++) u.h[i] = f2bf(s[i]);
    *(uint4*)(wrt + ((size_t)(ks * 256 + o) * 32 + j0)) = u.v;
  } else {                                   // w_span: [ks][mt][phys][32], phys=k2*16+g
    int c16 = id - 8192;                     // < 73728
    int j0  = (c16 & 3) * 8;
    int row = c16 >> 2;                      // < 18432
    int phys = row % 144;
    int mtks = row / 144;                    // ks*16 + mt
    int mt = mtks & 15, ks = mtks >> 4;
    int g = phys & 15, k2 = phys >> 4;
    int sg = mt * 144 + g * 9 + k2;          // s = (mt*16+g)*9 + k2
    const float* s = wsp + (size_t)sg * 256 + ks * 32 + j0;
    #pragma unroll
    for (int i = 0; i < 8; i++) u.h[i] = f2bf(s[i]);
    *(uint4*)(wspt + ((size_t)row * 32 + j0)) = u.v;
  }
}

// ---------------- kernel 1 (proven v1): Wr = w_reduce @ X + b_reduce, + BN partials ----------
__global__ __launch_bounds__(256) void k1_reduce_gemm(
    const float* __restrict__ X, const uint16_t* __restrict__ wrt,
    const float* __restrict__ bred, uint16_t* __restrict__ Wr,
    float* __restrict__ part){
  const int pt = blockIdx.x, mt = blockIdx.y, b = blockIdx.z;
  const int p0 = pt * 128, o0 = mt * 128;
  __shared__ __align__(16) uint16_t Al[2][128*32];
  __shared__ __align__(16) uint16_t Bl[2][128*32];
  __shared__ float redS[256], redQ[256];
  const int t = threadIdx.x;
  const int wv = t >> 6, lane = t & 63, q = lane >> 4, l = lane & 15;
  const int wm = wv >> 1, wn = wv & 1;
  const int c2 = (t & 15) * 2, seg = t >> 4;
  f32x4 acc[4][4] = {};
  union { float f[8]; float4 v[2]; } v0, v1;

  auto stageA = [&](int ks, int buf){
    const char* src = (const char*)(wrt + ((size_t)ks * 256 + o0) * 32);
    char* dst = (char*)(&Al[buf][0]);
    for (int cc = wv; cc < 8; cc += 4)
      glds16(src + cc*1024 + lane*16, dst + cc*1024);
  };
  auto loadB = [&](int ks){
    const float* s0 = X + ((size_t)(b * 256 + ks * 32 + c2)) * 4096 + p0 + seg * 8;
    const float* s1 = s0 + 4096;
    v0.v[0] = *(const float4*)(s0 + 0);
    v0.v[1] = *(const float4*)(s0 + 4);
    v1.v[0] = *(const float4*)(s1 + 0);
    v1.v[1] = *(const float4*)(s1 + 4);
  };
  auto writeB = [&](int buf){
    uint16_t* dst = &Bl[buf][(seg * 8) * 32 + c2];
    #pragma unroll
    for (int i = 0; i < 8; i++){
      uint32_t pk = (uint32_t)f2bf(v0.f[i]) | ((uint32_t)f2bf(v1.f[i]) << 16);
      *(uint32_t*)(dst + (size_t)i * 32) = pk;
    }
  };

  stageA(0, 0); loadB(0); writeB(0);
  __syncthreads();
  int cur = 0;
  for (int ks = 0; ks < 8; ks++){
    if (ks < 7){ stageA(ks + 1, cur ^ 1); loadB(ks + 1); }
    s16x8 af[4], bfv[4];
    #pragma unroll
    for (int mi = 0; mi < 4; mi++)
      af[mi] = *(const s16x8*)(&Al[cur][(wm*64 + mi*16 + l)*32 + q*8]);
    #pragma unroll
    for (int ni = 0; ni < 4; ni++)
      bfv[ni] = *(const s16x8*)(&Bl[cur][(wn*64 + ni*16 + l)*32 + q*8]);
    #pragma unroll
    for (int mi = 0; mi < 4; mi++)
      #pragma unroll
      for (int ni = 0; ni < 4; ni++)
        acc[mi][ni] = mfma16x16x32(af[mi], bfv[ni], acc[mi][ni], 0);
    if (ks < 7) writeB(cur ^ 1);
    __syncthreads();
    cur ^= 1;
  }
  // epilogue: +b_reduce, bf16 store (tiled), and per-channel partial sums
  float ssum[4][4] = {}, ssq[4][4] = {};
  #pragma unroll
  for (int mi = 0; mi < 4; mi++){
    int o = o0 + wm*64 + mi*16 + q*4;
    float4 br = *(const float4*)(bred + o);
    int slab = o >> 5, orem = o & 31;
    #pragma unroll
    for (int ni = 0; ni < 4; ni++){
      int p = p0 + wn*64 + ni*16 + l;
      f32x4 v = acc[mi][ni];
      float e0 = v[0] + br.x, e1 = v[1] + br.y, e2 = v[2] + br.z, e3 = v[3] + br.w;
      ssum[mi][0] += e0; ssq[mi][0] += e0*e0;
      ssum[mi][1] += e1; ssq[mi][1] += e1*e1;
      ssum[mi][2] += e2; ssq[mi][2] += e2*e2;
      ssum[mi][3] += e3; ssq[mi][3] += e3*e3;
      uint32_t lo = (uint32_t)f2bf(e0) | ((uint32_t)f2bf(e1) << 16);
      uint32_t hi = (uint32_t)f2bf(e2) | ((uint32_t)f2bf(e3) << 16);
      uint2 pk; pk.x = lo; pk.y = hi;
      *(uint2*)(Wr + ((size_t)((b*8 + slab)*4096 + p)) * 32 + orem) = pk;
    }
  }
  #pragma unroll
  for (int mi = 0; mi < 4; mi++)
    #pragma unroll
    for (int j = 0; j < 4; j++){
      #pragma unroll
      for (int off = 1; off < 16; off <<= 1){
        ssum[mi][j] += __shfl_xor(ssum[mi][j], off);
        ssq[mi][j]  += __shfl_xor(ssq[mi][j],  off);
      }
    }
  if (l == 0){
    #pragma unroll
    for (int mi = 0; mi < 4; mi++)
      #pragma unroll
      for (int j = 0; j < 4; j++){
        int ch_local = wm*64 + mi*16 + q*4 + j;   // [0,128)
        redS[ch_local*2 + wn] = ssum[mi][j];
        redQ[ch_local*2 + wn] = ssq[mi][j];
      }
  }
  __syncthreads();
  {
    int ch_local = t >> 1, m = t & 1;
    float val = m ? (redQ[ch_local*2] + redQ[ch_local*2+1])
                  : (redS[ch_local*2] + redS[ch_local*2+1]);
    int ch = o0 + ch_local;
    int idx = pt*16 + b;                         // [0,512)
    part[((size_t)ch*512 + idx)*2 + m] = val;
  }
}

// ---------------- kernel 2: finalize BN coeffs ----------------
__global__ __launch_bounds__(64) void bn_final(
    const float* __restrict__ part, const float* __restrict__ gamma,
    const float* __restrict__ beta, float* __restrict__ coeffs){
  int c = blockIdx.x, t = threadIdx.x;
  float s = 0.f, sq = 0.f;
  const float* p = part + (size_t)c * 1024;
  #pragma unroll
  for (int i = 0; i < 8; i++){
    float2 v = *(const float2*)(p + (t*8 + i)*2);
    s += v.x; sq += v.y;
  }
  #pragma unroll
  for (int off = 1; off < 64; off <<= 1){
    s  += __shfl_xor(s,  off);
    sq += __shfl_xor(sq, off);
  }
  if (t == 0){
    const float inv = 1.0f / 65536.0f;
    float mean = s * inv;
    float var  = sq * inv - mean * mean;
    float rstd = rsqrtf(var + 1e-5f);
    float A = gamma[c] * rstd;
    float Bc = beta[c] - mean * A;
    coeffs[2*c] = A; coeffs[2*c+1] = Bc;
  }
}

// ---------------- kernel 2c: Wn = relu(Wr*A + B) in-place, one pass ----------------
__global__ __launch_bounds__(256) void bn_apply(uint16_t* __restrict__ Wr,
                                                const float* __restrict__ coeffs){
  __shared__ float cf[512];
  cf[threadIdx.x]       = coeffs[threadIdx.x];
  cf[threadIdx.x + 256] = coeffs[threadIdx.x + 256];
  __syncthreads();
  #pragma unroll
  for (int it = 0; it < 4; it++){
    size_t c16 = (size_t)blockIdx.x * 256 + threadIdx.x + (size_t)it * (2048u*256u);
    uint16_t* pch = Wr + c16 * 8;
    int sj = (int)((c16 >> 14) & 7);       // slab (16384 chunks per (b,s))
    int j0 = (int)(c16 & 3) * 8;
    union { uint4 v; uint16_t h[8]; } u;
    u.v = *(const uint4*)pch;
    #pragma unroll
    for (int i = 0; i < 8; i++){
      int cch = sj * 32 + j0 + i;
      float v = bf2f(u.h[i]);
      v = fmaf(v, cf[2*cch], cf[2*cch+1]);
      v = fmaxf(v, 0.f);
      u.h[i] = f2bf(v);
    }
    *(uint4*)pch = u.v;
  }
}

// ---------------- kernel 3 v15: BN=512, 8 waves, proven per-wave schedule ----------------
// 512 threads (8 waves), each wave owns 64 output cols (wv*64..+63).
// Swapped MFMA operands (lane owns 4 consecutive output cols). 2-deep A
// staging (wave wv stages chunk wv; wv0 also chunk 8); B global->reg 2-deep.
// LDS = Al[2] 18,432 + Xl 16*684*4=43,776 + bsp 576 = 62,784 B -> 2 blocks/CU
// = 16 waves/CU (4/SIMD). Per-wave counted vmcnt identical FIFO math to r12.
__global__ __launch_bounds__(512) void k3_span_inv(
    const uint16_t* __restrict__ Wn, const uint16_t* __restrict__ wspt,
    const float* __restrict__ bspan, const float* __restrict__ X,
    float* __restrict__ out){
  const int orig = blockIdx.x;                       // 2048
  const int wgid = (orig & 7) * 256 + (orig >> 3);   // bijective XCD chunking
  const int mt = wgid & 15, pt = (wgid >> 4) & 7, b = wgid >> 7;
  const int p0 = pt * 512;
  __shared__ __align__(16) uint16_t Al[2][144*32];   // 18,432 B
  __shared__ __align__(16) float Xl[16*684];         // 43,776 B, ch stride 684
  __shared__ float bsp[144];
  const int t = threadIdx.x;
  const int wv = t >> 6, lane = t & 63, q = lane >> 4, l = lane & 15;
  const int qs = q ^ ((l >> 1) & 3);          // swizzled 16B slot for frag reads
  if (t < 144){
    int g = t & 15, k2 = t >> 4;
    bsp[t] = bspan[mt*144 + g*9 + k2];        // indexed by phys = k2*16+g
  }
  // zero halo dwords (cols -1 and 64 -> d=0 and d=65 in each of 10 rows)
  if (t < 320){
    int ch = t / 20, rr = t % 20, r = rr >> 1;
    Xl[ch*684 + r*68 + (rr & 1)*65] = 0.f;
  }
  PIN();
  f32x4 acc[9][4] = {};

  // per-lane swizzled global offset within each 1KB (16-row) chunk
  const int lsw = ((lane >> 2) << 6) + ((((lane & 3) ^ ((lane >> 3) & 3))) << 4);
  const char* Abase = (const char*)(wspt + (size_t)mt * (144*32));
  const size_t AslabB = (size_t)16 * 144 * 64;
  // B fragment lane addr: position row = p0 + wv*64 + ni*16 + l, k-slot q
  const uint16_t* Bb = Wn + (((size_t)(b*8))*4096 + p0 + wv*64 + l)*32 + q*8;
  const size_t BslabE = (size_t)4096 * 32;

  auto stageA = [&](int ks, int buf){
    const char* asrc = Abase + (size_t)ks * AslabB + lsw;
    char* adst = (char*)(&Al[buf][0]);
    glds16(asrc + (size_t)wv*1024, adst + wv*1024);
    if (wv == 0) glds16(asrc + 8*1024, adst + 8*1024);
  };

  s16x8 bb[2][4];
  float4 xv[5];
  // prologue: stage A(0) [1-2 glds], load B(0), B(1) [8 loads].
  // WAITV(8): keeps the 8 B loads, drains the stage for every wave.
  stageA(0, 0);
  PIN();
  #pragma unroll
  for (int ni = 0; ni < 4; ni++) bb[0][ni] = *(const s16x8*)(Bb + 0*BslabE + (size_t)ni*512);
  #pragma unroll
  for (int ni = 0; ni < 4; ni++) bb[1][ni] = *(const s16x8*)(Bb + 1*BslabE + (size_t)ni*512);
  PIN();
  WAITV(8);
  BAR();

  #pragma unroll
  for (int ks = 0; ks < 8; ks++){
    if (ks < 7) stageA(ks + 1, (ks + 1) & 1);
    PIN();
    if (ks == 0){
      // hoisted X-tile loads: 2560 float4 chunks, 5 per thread (clamped rows)
      #pragma unroll
      for (int i = 0; i < 5; i++){
        int v = t + i*512;
        int ch = v / 160, rem = v - ch*160;
        int r = rem >> 4, c4 = (rem & 15) * 4;
        int hr = pt*8 - 1 + r;
        int hrc = min(max(hr, 0), 63);
        xv[i] = *(const float4*)(X + ((size_t)(b*256 + mt*16 + ch))*4096 + hrc*64 + c4);
      }
      PIN();
    }
    if (ks == 1){
      // write X tile to LDS (xv drained by step-0's WAITV(4))
      #pragma unroll
      for (int i = 0; i < 5; i++){
        int v = t + i*512;
        int ch = v / 160, rem = v - ch*160;
        int r = rem >> 4, c4 = (rem & 15) * 4;
        int hr = pt*8 - 1 + r;
        bool ok = (hr >= 0) && (hr < 64);
        float4 val = xv[i];
        int d = ch*684 + r*68 + 1 + c4;
        Xl[d]   = ok ? val.x : 0.f;
        Xl[d+1] = ok ? val.y : 0.f;
        Xl[d+2] = ok ? val.z : 0.f;
        Xl[d+3] = ok ? val.w : 0.f;
      }
      PIN();
    }
    __builtin_amdgcn_s_setprio(1);
    #pragma unroll
    for (int mi = 0; mi < 9; mi++){
      s16x8 af = *(const s16x8*)(&Al[ks & 1][(mi*16 + l)*32 + qs*8]);
      // SWAPPED operands: acc row = position, col = group
      acc[mi][0] = mfma16x16x32(bb[ks & 1][0], af, acc[mi][0], 0);
      acc[mi][1] = mfma16x16x32(bb[ks & 1][1], af, acc[mi][1], 0);
      acc[mi][2] = mfma16x16x32(bb[ks & 1][2], af, acc[mi][2], 0);
      acc[mi][3] = mfma16x16x32(bb[ks & 1][3], af, acc[mi][3], 0);
    }
    __builtin_amdgcn_s_setprio(0);
    // prefetch B(ks+2) into the slot just consumed
    if (ks < 6){
      #pragma unroll
      for (int ni = 0; ni < 4; ni++)
        bb[ks & 1][ni] = *(const s16x8*)(Bb + (size_t)(ks+2)*BslabE + (size_t)ni*512);
    }
    if (ks < 7){
      if (ks < 6) { WAITV(4); } else { WAITV(0); }  // drain stage(ks+1)(+X at ks=0); keep B-prefetch
      WAITL0;                                        // my ds_reads (and Xl writes at ks=1) done
      BAR();
    }
  }

  // ---- involution epilogue (no barrier; Xl stable since step 1's BAR) ----
  // lane (q,l): channel gg = mt*16 + l, row h = pt*8+wv, cols ni*16+q*4+reg.
  float bs[9];
  #pragma unroll
  for (int k2 = 0; k2 < 9; k2++) bs[k2] = bsp[k2*16 + l];
  #pragma unroll
  for (int k2 = 0; k2 < 9; k2++)
    #pragma unroll
    for (int ni = 0; ni < 4; ni++){
      acc[k2][ni][0] += bs[k2]; acc[k2][ni][1] += bs[k2];
      acc[k2][ni][2] += bs[k2]; acc[k2][ni][3] += bs[k2];
    }
  const int h = pt*8 + wv;
  const int gg = mt*16 + l;
  float* Oc = out + ((size_t)(b*256 + gg) * 64 + h) * 64;
  const float* Xrow = &Xl[l*684 + wv*68];     // r = wv+dh
  #pragma unroll
  for (int ni = 0; ni < 4; ni++){
    f32x4 res = {0.f, 0.f, 0.f, 0.f};
    #pragma unroll
    for (int dh = 0; dh < 3; dh++){
      const float* xp = Xrow + dh*68 + ni*16 + q*4;   // 16B-aligned
      f32x4 xa = *(const f32x4*)xp;
      float2 xb = *(const float2*)(xp + 4);
      float x[6] = {xa[0], xa[1], xa[2], xa[3], xb.x, xb.y};
      #pragma unroll
      for (int dw = 0; dw < 3; dw++){
        const int k2 = dh*3 + dw;
        #pragma unroll
        for (int reg = 0; reg < 4; reg++)
          res[reg] = fmaf(acc[k2][ni][reg], x[reg + dw], res[reg]);
      }
    }
    *(f32x4*)(Oc + ni*16 + q*4) = res;
  }
}

extern "C" void kernel_launch(void* const* d_in, const int* in_sizes, int n_in,
                              void* d_out, int out_size, void* d_ws, size_t ws_size,
                              hipStream_t stream) {
  const float* X     = (const float*)d_in[0];
  const float* wred  = (const float*)d_in[1];
  const float* bred  = (const float*)d_in[2];
  const float* gamma = (const float*)d_in[3];
  const float* beta  = (const float*)d_in[4];
  const float* wsp   = (const float*)d_in[5];
  const float* bsp   = (const float*)d_in[6];
  float* out = (float*)d_out;

  char* ws = (char*)d_ws;
  uint16_t* Wr   = (uint16_t*)(ws);
  uint16_t* wrt  = (uint16_t*)(ws + 33554432);
  uint16_t* wspt = (uint16_t*)(ws + 33554432 + 131072);
  float* part    = (float*)(ws + 33554432 + 131072 + 1179648);
  float* coeffs  = (float*)(ws + 33554432 + 131072 + 1179648 + 1048576);
  if (ws_size < (size_t)(33554432 + 131072 + 1179648 + 1048576 + 2048)) return;

  prep_weights<<<320, 256, 0, stream>>>(wred, wsp, wrt, wspt);
  k1_reduce_gemm<<<dim3(32, 2, 16), 256, 0, stream>>>(X, wrt, bred, Wr, part);
  bn_final<<<256, 64, 0, stream>>>(part, gamma, beta, coeffs);
  bn_apply<<<2048, 256, 0, stream>>>(Wr, coeffs);
  k3_span_inv<<<2048, 512, 0, stream>>>(Wr, wspt, bsp, X, out);
}

// Round 16
// 134.094 us; speedup vs baseline: 1.1159x; 1.1159x over previous
//
#include <hip/hip_runtime.h>
#include <stdint.h>

// Inv2d fused pipeline, MI355X gfx950. ROUND-9 BEST CONFIG RESTORED.
// B=16, C=256, H=W=64, K2=9. All inputs fp32; internal GEMMs in bf16 MFMA.
//
// Pipeline: prep -> k1 v1 (GEMM1 + fused BN partial stats) -> bn_final ->
// bn_apply (one-pass ReLU(A*Wr+B) in-place) -> k3 v8 (3-deep A staging via
// global_load_lds + both-sides swizzle, B global->reg 2-deep, counted
// per-wave vmcnt, swapped-operand epilogue, stride-412 X tile).
//
// ws layout:
//   Wr (bf16, tiled [b][slab=c/32][p][c%32])      : 33,554,432 B
//   w_reduce bf16 tiled [ks][o][32]               :    131,072 B
//   w_span  bf16 tiled [ks][mt][phys=k2*16+g][32] :  1,179,648 B
//   part [c][512][2] f32 partial sums             :  1,048,576 B
//   coeffs [c][2] f32 (A=gamma*rstd, B=beta-mean*A):      2,048 B

typedef __attribute__((ext_vector_type(4))) float f32x4;
typedef __attribute__((ext_vector_type(8))) short s16x8;
typedef __attribute__((ext_vector_type(8))) __bf16 bf16x8;

#define WAITV(N) asm volatile("s_waitcnt vmcnt(" #N ")" ::: "memory")
#define WAITL0   asm volatile("s_waitcnt lgkmcnt(0)" ::: "memory")
#define PIN()    asm volatile("" ::: "memory")
#define BAR()    do { PIN(); __builtin_amdgcn_s_barrier(); PIN(); } while (0)

__device__ __forceinline__ float bf2f(uint16_t u){
  union { uint32_t i; float f; } v; v.i = ((uint32_t)u) << 16; return v.f;
}
__device__ __forceinline__ uint16_t f2bf(float f){
  __bf16 h = (__bf16)f;                       // compiler RNE cvt (m240)
  return __builtin_bit_cast(uint16_t, h);
}

// SFINAE shim: prefer short8 operands; fall back to __bf16 vec.
template <typename V>
__device__ __forceinline__ auto mfma16x16x32(V a, V b, f32x4 c, int)
    -> decltype(__builtin_amdgcn_mfma_f32_16x16x32_bf16(a, b, c, 0, 0, 0)) {
  return __builtin_amdgcn_mfma_f32_16x16x32_bf16(a, b, c, 0, 0, 0);
}
template <typename V>
__device__ __forceinline__ f32x4 mfma16x16x32(V a, V b, f32x4 c, long) {
  bf16x8 aa = __builtin_bit_cast(bf16x8, a);
  bf16x8 bb = __builtin_bit_cast(bf16x8, b);
  return __builtin_amdgcn_mfma_f32_16x16x32_bf16(aa, bb, c, 0, 0, 0);
}

typedef uint32_t u32_g __attribute__((address_space(1)));
typedef uint32_t u32_l __attribute__((address_space(3)));
__device__ __forceinline__ void glds16(const void* g, void* l){
  __builtin_amdgcn_global_load_lds((const u32_g*)g, (u32_l*)l, 16, 0, 0);
}

// ---------------- kernel 0: weight convert + pre-tile ----------------
__global__ __launch_bounds__(256) void prep_weights(
    const float* __restrict__ wred, const float* __restrict__ wsp,
    uint16_t* __restrict__ wrt, uint16_t* __restrict__ wspt){
  int id = blockIdx.x * 256 + threadIdx.x;   // 16B-chunk id, 320*256 = 81920 total
  union { uint4 v; uint16_t h[8]; } u;
  if (id < 8192){                            // w_reduce: [ks][o][32]
    int ks = id >> 10;
    int o  = (id >> 2) & 255;
    int j0 = (id & 3) * 8;
    const float* s = wred + o * 256 + ks * 32 + j0;
    #pragma unroll
    for (int i = 0; i < 8; i++) u.h[i] = f2bf(s[i]);
    *(uint4*)(wrt + ((size_t)(ks * 256 + o) * 32 + j0)) = u.v;
  } else {                                   // w_span: [ks][mt][phys][32], phys=k2*16+g
    int c16 = id - 8192;                     // < 73728
    int j0  = (c16 & 3) * 8;
    int row = c16 >> 2;                      // < 18432
    int phys = row % 144;
    int mtks = row / 144;                    // ks*16 + mt
    int mt = mtks & 15, ks = mtks >> 4;
    int g = phys & 15, k2 = phys >> 4;
    int sg = mt * 144 + g * 9 + k2;          // s = (mt*16+g)*9 + k2
    const float* s = wsp + (size_t)sg * 256 + ks * 32 + j0;
    #pragma unroll
    for (int i = 0; i < 8; i++) u.h[i] = f2bf(s[i]);
    *(uint4*)(wspt + ((size_t)row * 32 + j0)) = u.v;
  }
}

// ---------------- kernel 1 v1: Wr = w_reduce @ X + b_reduce, + fused BN partials ----------
__global__ __launch_bounds__(256) void k1_reduce_gemm(
    const float* __restrict__ X, const uint16_t* __restrict__ wrt,
    const float* __restrict__ bred, uint16_t* __restrict__ Wr,
    float* __restrict__ part){
  const int pt = blockIdx.x, mt = blockIdx.y, b = blockIdx.z;
  const int p0 = pt * 128, o0 = mt * 128;
  __shared__ __align__(16) uint16_t Al[2][128*32];
  __shared__ __align__(16) uint16_t Bl[2][128*32];
  __shared__ float redS[256], redQ[256];
  const int t = threadIdx.x;
  const int wv = t >> 6, lane = t & 63, q = lane >> 4, l = lane & 15;
  const int wm = wv >> 1, wn = wv & 1;
  const int c2 = (t & 15) * 2, seg = t >> 4;
  f32x4 acc[4][4] = {};
  union { float f[8]; float4 v[2]; } v0, v1;

  auto stageA = [&](int ks, int buf){
    const char* src = (const char*)(wrt + ((size_t)ks * 256 + o0) * 32);
    char* dst = (char*)(&Al[buf][0]);
    for (int cc = wv; cc < 8; cc += 4)
      glds16(src + cc*1024 + lane*16, dst + cc*1024);
  };
  auto loadB = [&](int ks){
    const float* s0 = X + ((size_t)(b * 256 + ks * 32 + c2)) * 4096 + p0 + seg * 8;
    const float* s1 = s0 + 4096;
    v0.v[0] = *(const float4*)(s0 + 0);
    v0.v[1] = *(const float4*)(s0 + 4);
    v1.v[0] = *(const float4*)(s1 + 0);
    v1.v[1] = *(const float4*)(s1 + 4);
  };
  auto writeB = [&](int buf){
    uint16_t* dst = &Bl[buf][(seg * 8) * 32 + c2];
    #pragma unroll
    for (int i = 0; i < 8; i++){
      uint32_t pk = (uint32_t)f2bf(v0.f[i]) | ((uint32_t)f2bf(v1.f[i]) << 16);
      *(uint32_t*)(dst + (size_t)i * 32) = pk;
    }
  };

  stageA(0, 0); loadB(0); writeB(0);
  __syncthreads();
  int cur = 0;
  for (int ks = 0; ks < 8; ks++){
    if (ks < 7){ stageA(ks + 1, cur ^ 1); loadB(ks + 1); }
    s16x8 af[4], bfv[4];
    #pragma unroll
    for (int mi = 0; mi < 4; mi++)
      af[mi] = *(const s16x8*)(&Al[cur][(wm*64 + mi*16 + l)*32 + q*8]);
    #pragma unroll
    for (int ni = 0; ni < 4; ni++)
      bfv[ni] = *(const s16x8*)(&Bl[cur][(wn*64 + ni*16 + l)*32 + q*8]);
    #pragma unroll
    for (int mi = 0; mi < 4; mi++)
      #pragma unroll
      for (int ni = 0; ni < 4; ni++)
        acc[mi][ni] = mfma16x16x32(af[mi], bfv[ni], acc[mi][ni], 0);
    if (ks < 7) writeB(cur ^ 1);
    __syncthreads();
    cur ^= 1;
  }
  // epilogue: +b_reduce, bf16 store (tiled), and per-channel partial sums
  float ssum[4][4] = {}, ssq[4][4] = {};
  #pragma unroll
  for (int mi = 0; mi < 4; mi++){
    int o = o0 + wm*64 + mi*16 + q*4;
    float4 br = *(const float4*)(bred + o);
    int slab = o >> 5, orem = o & 31;
    #pragma unroll
    for (int ni = 0; ni < 4; ni++){
      int p = p0 + wn*64 + ni*16 + l;
      f32x4 v = acc[mi][ni];
      float e0 = v[0] + br.x, e1 = v[1] + br.y, e2 = v[2] + br.z, e3 = v[3] + br.w;
      ssum[mi][0] += e0; ssq[mi][0] += e0*e0;
      ssum[mi][1] += e1; ssq[mi][1] += e1*e1;
      ssum[mi][2] += e2; ssq[mi][2] += e2*e2;
      ssum[mi][3] += e3; ssq[mi][3] += e3*e3;
      uint32_t lo = (uint32_t)f2bf(e0) | ((uint32_t)f2bf(e1) << 16);
      uint32_t hi = (uint32_t)f2bf(e2) | ((uint32_t)f2bf(e3) << 16);
      uint2 pk; pk.x = lo; pk.y = hi;
      *(uint2*)(Wr + ((size_t)((b*8 + slab)*4096 + p)) * 32 + orem) = pk;
    }
  }
  #pragma unroll
  for (int mi = 0; mi < 4; mi++)
    #pragma unroll
    for (int j = 0; j < 4; j++){
      #pragma unroll
      for (int off = 1; off < 16; off <<= 1){
        ssum[mi][j] += __shfl_xor(ssum[mi][j], off);
        ssq[mi][j]  += __shfl_xor(ssq[mi][j],  off);
      }
    }
  if (l == 0){
    #pragma unroll
    for (int mi = 0; mi < 4; mi++)
      #pragma unroll
      for (int j = 0; j < 4; j++){
        int ch_local = wm*64 + mi*16 + q*4 + j;   // [0,128)
        redS[ch_local*2 + wn] = ssum[mi][j];
        redQ[ch_local*2 + wn] = ssq[mi][j];
      }
  }
  __syncthreads();
  {
    int ch_local = t >> 1, m = t & 1;
    float val = m ? (redQ[ch_local*2] + redQ[ch_local*2+1])
                  : (redS[ch_local*2] + redS[ch_local*2+1]);
    int ch = o0 + ch_local;
    int idx = pt*16 + b;                         // [0,512)
    part[((size_t)ch*512 + idx)*2 + m] = val;
  }
}

// ---------------- kernel 2: finalize BN coeffs ----------------
__global__ __launch_bounds__(64) void bn_final(
    const float* __restrict__ part, const float* __restrict__ gamma,
    const float* __restrict__ beta, float* __restrict__ coeffs){
  int c = blockIdx.x, t = threadIdx.x;
  float s = 0.f, sq = 0.f;
  const float* p = part + (size_t)c * 1024;
  #pragma unroll
  for (int i = 0; i < 8; i++){
    float2 v = *(const float2*)(p + (t*8 + i)*2);
    s += v.x; sq += v.y;
  }
  #pragma unroll
  for (int off = 1; off < 64; off <<= 1){
    s  += __shfl_xor(s,  off);
    sq += __shfl_xor(sq, off);
  }
  if (t == 0){
    const float inv = 1.0f / 65536.0f;
    float mean = s * inv;
    float var  = sq * inv - mean * mean;
    float rstd = rsqrtf(var + 1e-5f);
    float A = gamma[c] * rstd;
    float Bc = beta[c] - mean * A;
    coeffs[2*c] = A; coeffs[2*c+1] = Bc;
  }
}

// ---------------- kernel 2c: Wn = relu(Wr*A + B) in-place, one pass ----------------
__global__ __launch_bounds__(256) void bn_apply(uint16_t* __restrict__ Wr,
                                                const float* __restrict__ coeffs){
  __shared__ float cf[512];
  cf[threadIdx.x]       = coeffs[threadIdx.x];
  cf[threadIdx.x + 256] = coeffs[threadIdx.x + 256];
  __syncthreads();
  #pragma unroll
  for (int it = 0; it < 4; it++){
    size_t c16 = (size_t)blockIdx.x * 256 + threadIdx.x + (size_t)it * (2048u*256u);
    uint16_t* pch = Wr + c16 * 8;
    int sj = (int)((c16 >> 14) & 7);       // slab (16384 chunks per (b,s))
    int j0 = (int)(c16 & 3) * 8;
    union { uint4 v; uint16_t h[8]; } u;
    u.v = *(const uint4*)pch;
    #pragma unroll
    for (int i = 0; i < 8; i++){
      int cch = sj * 32 + j0 + i;
      float v = bf2f(u.h[i]);
      v = fmaf(v, cf[2*cch], cf[2*cch+1]);
      v = fmaxf(v, 0.f);
      u.h[i] = f2bf(v);
    }
    *(uint4*)pch = u.v;
  }
}

// ---------------- kernel 3 v8 (round-9 proven best): GEMM2 + fused involution ----------------
// 256 threads (4 waves). Swapped MFMA operands (lane owns 4 consecutive output
// cols). 3-deep A staging; per-wave counted vmcnt; B global->reg 2-deep.
// X tile loads at step 0, LDS writes at step 1; channel stride 412.
__global__ __launch_bounds__(256, 2) void k3_span_inv(
    const uint16_t* __restrict__ Wn, const uint16_t* __restrict__ wspt,
    const float* __restrict__ bspan, const float* __restrict__ X,
    float* __restrict__ out){
  const int orig = blockIdx.x;                       // 4096
  const int wgid = (orig & 7) * 512 + (orig >> 3);   // bijective XCD chunking
  const int mt = wgid & 15, pt = (wgid >> 4) & 15, b = wgid >> 8;
  const int p0 = pt * 256;
  __shared__ __align__(16) uint16_t Al[3][144*32];   // 27,648 B
  __shared__ __align__(16) float Xl[16*412];         // 26,368 B, ch stride 412
  __shared__ float bsp[144];
  const int t = threadIdx.x;
  const int wv = t >> 6, lane = t & 63, q = lane >> 4, l = lane & 15;
  const int qs = q ^ ((l >> 1) & 3);          // swizzled 16B slot for frag reads
  if (t < 144){
    int g = t & 15, k2 = t >> 4;
    bsp[t] = bspan[mt*144 + g*9 + k2];        // indexed by phys = k2*16+g
  }
  // zero halo dwords (cols -1 and 64 -> d=0 and d=65 within each row)
  if (t < 192){
    int ch = t / 12, rr = t % 12, r = rr >> 1;
    Xl[ch*412 + r*68 + (rr & 1)*65] = 0.f;
  }
  PIN();
  f32x4 acc[9][4] = {};

  // per-lane swizzled global offset within each 1KB (16-row) chunk
  const int lsw = ((lane >> 2) << 6) + ((((lane & 3) ^ ((lane >> 3) & 3))) << 4);
  const char* Abase = (const char*)(wspt + (size_t)mt * (144*32));
  const size_t AslabB = (size_t)16 * 144 * 64;
  // B fragment lane addr: position row = p0 + wv*64 + ni*16 + l, k-slot q
  const uint16_t* Bb = Wn + (((size_t)(b*8))*4096 + p0 + wv*64 + l)*32 + q*8;
  const size_t BslabE = (size_t)4096 * 32;

  auto stageA = [&](int ks, int buf){
    const char* asrc = Abase + (size_t)ks * AslabB + lsw;
    char* adst = (char*)(&Al[buf][0]);
    glds16(asrc + (size_t)wv*1024,     adst + wv*1024);
    glds16(asrc + (size_t)(wv+4)*1024, adst + (wv+4)*1024);
    if (wv == 0) glds16(asrc + 8*1024, adst + 8*1024);
  };

  s16x8 bb[2][4];
  float4 xv[6];
  // prologue: stage0, B(0), B(1), stage1; drain stage0+B(0) only.
  stageA(0, 0);
  PIN();
  #pragma unroll
  for (int ni = 0; ni < 4; ni++) bb[0][ni] = *(const s16x8*)(Bb + 0*BslabE + (size_t)ni*512);
  #pragma unroll
  for (int ni = 0; ni < 4; ni++) bb[1][ni] = *(const s16x8*)(Bb + 1*BslabE + (size_t)ni*512);
  PIN();
  stageA(1, 1);
  PIN();
  if (wv == 0) { WAITV(7); } else { WAITV(6); }   // leaves B(1)+stage1 in flight
  WAITL0;
  BAR();

  #pragma unroll
  for (int ks = 0; ks < 8; ks++){
    if (ks < 6) stageA(ks + 2, (ks + 2) % 3);
    PIN();
    if (ks == 0){
      // hoisted X-tile loads (clamped rows; zeroed at write time)
      #pragma unroll
      for (int i = 0; i < 6; i++){
        int v = t + i*256;
        int ch = v / 96, rem = v - ch*96;
        int r = rem >> 4, c4 = (rem & 15) * 4;
        int hr = pt*4 - 1 + r;
        int hrc = min(max(hr, 0), 63);
        xv[i] = *(const float4*)(X + ((size_t)(b*256 + mt*16 + ch))*4096 + hrc*64 + c4);
      }
      PIN();
    }
    if (ks == 1){
      // write X tile to LDS (compiler auto-waits xv's vmcnt; drained before use)
      #pragma unroll
      for (int i = 0; i < 6; i++){
        int v = t + i*256;
        int ch = v / 96, rem = v - ch*96;
        int r = rem >> 4, c4 = (rem & 15) * 4;
        int hr = pt*4 - 1 + r;
        bool ok = (hr >= 0) && (hr < 64);
        float4 val = xv[i];
        int d = ch*412 + r*68 + 1 + c4;
        Xl[d]   = ok ? val.x : 0.f;
        Xl[d+1] = ok ? val.y : 0.f;
        Xl[d+2] = ok ? val.z : 0.f;
        Xl[d+3] = ok ? val.w : 0.f;
      }
      PIN();
    }
    __builtin_amdgcn_s_setprio(1);
    #pragma unroll
    for (int mi = 0; mi < 9; mi++){
      s16x8 af = *(const s16x8*)(&Al[ks % 3][(mi*16 + l)*32 + qs*8]);
      // SWAPPED operands: acc row = position, col = group
      acc[mi][0] = mfma16x16x32(bb[ks & 1][0], af, acc[mi][0], 0);
      acc[mi][1] = mfma16x16x32(bb[ks & 1][1], af, acc[mi][1], 0);
      acc[mi][2] = mfma16x16x32(bb[ks & 1][2], af, acc[mi][2], 0);
      acc[mi][3] = mfma16x16x32(bb[ks & 1][3], af, acc[mi][3], 0);
    }
    __builtin_amdgcn_s_setprio(0);
    // prefetch B(ks+2) into the slot just consumed
    if (ks < 6){
      #pragma unroll
      for (int ni = 0; ni < 4; ni++)
        bb[ks & 1][ni] = *(const s16x8*)(Bb + (size_t)(ks+2)*BslabE + (size_t)ni*512);
    }
    if (ks < 7){
      // drain: A(ks+1) and B(ks+1) (issued a full step earlier).
      if (ks == 0){
        if (wv == 0) { WAITV(13); } else { WAITV(12); }  // keep stage2+X+B2 in flight
      } else if (ks < 6){
        if (wv == 0) { WAITV(7); } else { WAITV(6); }    // keep stage(ks+2)+B(ks+2)
      } else {
        WAITV(0);                                        // ks==6: all must land
      }
      WAITL0;          // my ds_reads (and Xl writes at ks=1) complete
      BAR();
    }
  }

  // ---- involution epilogue (no barrier needed; Xl visible since step 1) ----
  // lane (q,l): channel gg = mt*16 + l, row h = pt*4+wv, cols ni*16+q*4+reg.
  float bs[9];
  #pragma unroll
  for (int k2 = 0; k2 < 9; k2++) bs[k2] = bsp[k2*16 + l];
  #pragma unroll
  for (int k2 = 0; k2 < 9; k2++)
    #pragma unroll
    for (int ni = 0; ni < 4; ni++){
      acc[k2][ni][0] += bs[k2]; acc[k2][ni][1] += bs[k2];
      acc[k2][ni][2] += bs[k2]; acc[k2][ni][3] += bs[k2];
    }
  const int h = pt*4 + wv;
  const int gg = mt*16 + l;
  float* Oc = out + ((size_t)(b*256 + gg) * 64 + h) * 64;
  const float* Xrow = &Xl[l*412 + wv*68];     // r = wv+dh
  #pragma unroll
  for (int ni = 0; ni < 4; ni++){
    f32x4 res = {0.f, 0.f, 0.f, 0.f};
    #pragma unroll
    for (int dh = 0; dh < 3; dh++){
      const float* xp = Xrow + dh*68 + ni*16 + q*4;   // 16B-aligned
      f32x4 xa = *(const f32x4*)xp;
      float2 xb = *(const float2*)(xp + 4);
      float x[6] = {xa[0], xa[1], xa[2], xa[3], xb.x, xb.y};
      #pragma unroll
      for (int dw = 0; dw < 3; dw++){
        const int k2 = dh*3 + dw;
        #pragma unroll
        for (int reg = 0; reg < 4; reg++)
          res[reg] = fmaf(acc[k2][ni][reg], x[reg + dw], res[reg]);
      }
    }
    *(f32x4*)(Oc + ni*16 + q*4) = res;
  }
}

extern "C" void kernel_launch(void* const* d_in, const int* in_sizes, int n_in,
                              void* d_out, int out_size, void* d_ws, size_t ws_size,
                              hipStream_t stream) {
  const float* X     = (const float*)d_in[0];
  const float* wred  = (const float*)d_in[1];
  const float* bred  = (const float*)d_in[2];
  const float* gamma = (const float*)d_in[3];
  const float* beta  = (const float*)d_in[4];
  const float* wsp   = (const float*)d_in[5];
  const float* bsp   = (const float*)d_in[6];
  float* out = (float*)d_out;

  char* ws = (char*)d_ws;
  uint16_t* Wr   = (uint16_t*)(ws);
  uint16_t* wrt  = (uint16_t*)(ws + 33554432);
  uint16_t* wspt = (uint16_t*)(ws + 33554432 + 131072);
  float* part    = (float*)(ws + 33554432 + 131072 + 1179648);
  float* coeffs  = (float*)(ws + 33554432 + 131072 + 1179648 + 1048576);
  if (ws_size < (size_t)(33554432 + 131072 + 1179648 + 1048576 + 2048)) return;

  prep_weights<<<320, 256, 0, stream>>>(wred, wsp, wrt, wspt);
  k1_reduce_gemm<<<dim3(32, 2, 16), 256, 0, stream>>>(X, wrt, bred, Wr, part);
  bn_final<<<256, 64, 0, stream>>>(part, gamma, beta, coeffs);
  bn_apply<<<2048, 256, 0, stream>>>(Wr, coeffs);
  k3_span_inv<<<4096, 256, 0, stream>>>(Wr, wspt, bsp, X, out);
}